// Round 7
// baseline (2948.290 us; speedup 1.0000x reference)
//
#include <hip/hip_runtime.h>
#include <hip/hip_bf16.h>

typedef _Float16 f16;
typedef f16 f16x2 __attribute__((ext_vector_type(2)));
typedef f16 f16x4 __attribute__((ext_vector_type(4)));
typedef f16 f16x8 __attribute__((ext_vector_type(8)));
typedef float f32x4 __attribute__((ext_vector_type(4)));

__device__ __forceinline__ float sigmoid_f(float x) {
    return __builtin_amdgcn_rcpf(1.f + __expf(-x));
}
__device__ __forceinline__ float tanh_f(float x) {
    return 1.f - 2.f * __builtin_amdgcn_rcpf(__expf(2.f * x) + 1.f);
}

// MFMA with forced AGPR residence. POS: 1 = chain head (protect VALU zero-init
// -> SrcC read with s_nop), 2 = chain tail (protect MFMA -> v_accvgpr_read
// with 16 cycles of nops), 0 = middle (back-to-back accumulate is legal).
template <int POS>
__device__ __forceinline__ void mfma16(f32x4& d, f16x8 a, f16x8 b) {
    if constexpr (POS == 1)
        asm volatile("s_nop 1\n\tv_mfma_f32_16x16x32_f16 %0, %1, %2, %0"
                     : "+a"(d) : "a"(a), "v"(b));
    else if constexpr (POS == 2)
        asm volatile("v_mfma_f32_16x16x32_f16 %0, %1, %2, %0\n\ts_nop 7\n\ts_nop 7"
                     : "+a"(d) : "a"(a), "v"(b));
    else
        asm volatile("v_mfma_f32_16x16x32_f16 %0, %1, %2, %0"
                     : "+a"(d) : "a"(a), "v"(b));
}

// ------------------------------------------------- fused weight f32->f16 convert
// bias_cat[1536] = bih + (bhh for r,z thirds); bhn16[512] = (f16)bhh_n per GRU.
// Weight float4 count is 221184 (Wb = 256x256 = 16384 float4).
__global__ __launch_bounds__(256) void cvt_weights_kernel(
    const float* __restrict__ wp, const float* __restrict__ wia, const float* __restrict__ wha,
    const float* __restrict__ wib, const float* __restrict__ whb, const float* __restrict__ wb,
    const float* __restrict__ bia, const float* __restrict__ bha,
    const float* __restrict__ bib, const float* __restrict__ bhb,
    f16* __restrict__ o_wp, f16* __restrict__ o_wia, f16* __restrict__ o_wha,
    f16* __restrict__ o_wib, f16* __restrict__ o_whb, f16* __restrict__ o_wb,
    float* __restrict__ bias_cat, f16* __restrict__ bhn16)
{
    int i = blockIdx.x * 256 + threadIdx.x;
    if (i < 221184) {
        const float* s; f16* d; int off;
        if      (i < 8192)   { s = wp;  d = o_wp;  off = i; }
        else if (i < 57344)  { s = wia; d = o_wia; off = i - 8192; }
        else if (i < 106496) { s = wha; d = o_wha; off = i - 57344; }
        else if (i < 155648) { s = wib; d = o_wib; off = i - 106496; }
        else if (i < 204800) { s = whb; d = o_whb; off = i - 155648; }
        else                 { s = wb;  d = o_wb;  off = i - 204800; }
        float4 f = ((const float4*)s)[off];
        f16x2 p0; p0.x = (f16)f.x; p0.y = (f16)f.y;
        f16x2 p1; p1.x = (f16)f.z; p1.y = (f16)f.w;
        ((f16x2*)d)[off * 2]     = p0;
        ((f16x2*)d)[off * 2 + 1] = p1;
    } else if (i < 221568) {
        int c0 = (i - 221184) * 4;
        float4 v;
        float* pv = (float*)&v;
#pragma unroll
        for (int u = 0; u < 4; ++u) {
            int c = c0 + u;
            int g = c >= 768;
            int local = c - 768 * g;
            const float* bi = g ? bib : bia;
            const float* bh = g ? bhb : bha;
            float val = bi[local];
            if (local < 512) val += bh[local];
            pv[u] = val;
        }
        *(float4*)(bias_cat + c0) = v;
    } else if (i < 221696) {
        int c0 = (i - 221568) * 4;
        f16x4 v;
#pragma unroll
        for (int u = 0; u < 4; ++u) {
            int c = c0 + u;
            int g = c >= 256;
            int local = c - 256 * g;
            const float* bh = g ? bhb : bha;
            v[u] = (f16)bh[512 + local];
        }
        *(f16x4*)(bhn16 + c0) = v;
    }
}

// ---------------------------------------------------------------- MFMA GEMM
#define BM 128
#define BN 128
#define BKC 64
#define LPAD 8

template <int KT, int NOUT, int EPI, bool CVTA, int BSPLIT>
__global__ __launch_bounds__(256) void gemm_kernel(
    const void* __restrict__ Araw, const f16* __restrict__ B,
    const float* __restrict__ bias, const float* __restrict__ bias2,
    f16* __restrict__ out16, const f16* __restrict__ xp16)
{
    __shared__ __align__(16) f16 As[BM][BKC + LPAD];
    __shared__ __align__(16) f16 Bs[BN][BKC + LPAD];
    int tid = threadIdx.x;
    int m0 = blockIdx.x * BM, n0 = blockIdx.y * BN;
    int wave = tid >> 6, lane = tid & 63;
    int wm = (wave & 1) * 64, wn = (wave >> 1) * 64;
    int quad = lane >> 4, l16 = lane & 15;

    f32x4 acc[4][4] = {};

    for (int kc = 0; kc < KT / BKC; ++kc) {
        __syncthreads();
#pragma unroll
        for (int i = 0; i < 4; ++i) {
            int idx = i * 256 + tid;
            int row = idx >> 3, c8 = idx & 7;
            if (CVTA) {
                const float* A32 = (const float*)Araw;
                const float* src = A32 + (size_t)(m0 + row) * KT + kc * BKC + c8 * 8;
                float4 fa = *(const float4*)src;
                float4 fb = *(const float4*)(src + 4);
                f16x8 h8;
                h8[0] = (f16)fa.x; h8[1] = (f16)fa.y; h8[2] = (f16)fa.z; h8[3] = (f16)fa.w;
                h8[4] = (f16)fb.x; h8[5] = (f16)fb.y; h8[6] = (f16)fb.z; h8[7] = (f16)fb.w;
                *(f16x8*)&As[row][c8 * 8] = h8;
            } else {
                const f16* A16 = (const f16*)Araw;
                uint4 va = *(const uint4*)(A16 + (size_t)(m0 + row) * KT + kc * BKC + c8 * 8);
                *(uint4*)&As[row][c8 * 8] = va;
            }
            uint4 vb = *(const uint4*)(B + (size_t)(n0 + row) * KT + kc * BKC + c8 * 8);
            *(uint4*)&Bs[row][c8 * 8] = vb;
        }
        __syncthreads();
#pragma unroll
        for (int kk = 0; kk < 2; ++kk) {
            f16x8 af[4], bf[4];
#pragma unroll
            for (int i = 0; i < 4; ++i) {
                af[i] = *(const f16x8*)&As[wm + i * 16 + l16][kk * 32 + quad * 8];
                bf[i] = *(const f16x8*)&Bs[wn + i * 16 + l16][kk * 32 + quad * 8];
            }
#pragma unroll
            for (int mi = 0; mi < 4; ++mi)
#pragma unroll
                for (int ni = 0; ni < 4; ++ni)
                    acc[mi][ni] = __builtin_amdgcn_mfma_f32_16x16x32_f16(af[mi], bf[ni], acc[mi][ni], 0, 0, 0);
        }
    }

#pragma unroll
    for (int ni = 0; ni < 4; ++ni) {
        int col = n0 + wn + ni * 16 + l16;
        float bv = (col < BSPLIT) ? bias[col] : bias2[col - BSPLIT];
#pragma unroll
        for (int mi = 0; mi < 4; ++mi) {
#pragma unroll
            for (int r = 0; r < 4; ++r) {
                int row = m0 + wm + mi * 16 + quad * 4 + r;
                float val = acc[mi][ni][r] + bv;
                if (EPI == 2) {
                    float tb = tanh_f(val);
                    float xpv = (float)xp16[(size_t)row * NOUT + col];
                    out16[(size_t)row * NOUT + col] = (f16)(tb * xpv);
                } else {
                    out16[(size_t)row * NOUT + col] = (f16)val;
                }
            }
        }
    }
}

// ---------------------------------------------------------------- GRU recurrence
// ROUND-7: MFMA recurrence with forced AGPR residence (inline asm).
// Round-6 PMC decode: MfmaUtil-per-active-CU 20.5% == 1536cy MFMA floor /
// 7450cy measured step. Excess = (a) ~175 extra VALU instr/wave/step =
// compiler shuttling wfrag/acc between arch and acc files (demand 128 exactly);
// (b) 4.7M LDS bank conflicts (~4.5cy x 128 B-frag reads/step).
// Fixes: (1) v_mfma inline asm, wfrag pinned "a", acc "+a" - MFMA sources
// AGPRs natively (v_dot2 could not - rounds 4/5). Hazard nops fused into
// chain head/tail asm. (2) h buffer 512B row stride + XOR-16B-slot swizzle
// (slot ^ (row&7)) applied on BOTH write and read. (3) reg diet: no xW
// prefetch (same-step load hides under ~2000cy dot+gate window), bhh_n as f16
// table, SGPR-base+voffset addressing for xW/hout.
#define XWS 1536

__global__ __launch_bounds__(1024)
__attribute__((amdgpu_waves_per_eu(4, 4)))
void rnn_kernel(
    const f16* __restrict__ xw_cat,
    const f16* __restrict__ whha, const f16* __restrict__ whhb,
    const f16* __restrict__ bhn16,
    f16* __restrict__ xa16, f16* __restrict__ xb16)
{
    int g  = blockIdx.x & 1;
    int bg = blockIdx.x >> 1;            // batch group 0..7 (16 batches each)
    int t = threadIdx.x;
    int wv = t >> 6;                     // wave 0..15: h-rows [wv*16, wv*16+16)
    int lane = t & 63;
    int l16 = lane & 15, quad = lane >> 4;
    int l8 = l16 & 7;

    const f16* whh = g ? whhb : whha;

    // A-fragments: [gate][kt], lane l: Whh[256*gate + wv*16 + l16][kt*32 + quad*8 +:8]
    f16x8 wfrag[3][8];
#pragma unroll
    for (int gate = 0; gate < 3; ++gate) {
        const f16* src = whh + (size_t)(gate * 256 + wv * 16 + l16) * 256 + quad * 8;
#pragma unroll
        for (int kt = 0; kt < 8; ++kt)
            wfrag[gate][kt] = *(const f16x8*)(src + kt * 32);
    }
#pragma unroll
    for (int gate = 0; gate < 3; ++gate)
#pragma unroll
        for (int kt = 0; kt < 8; ++kt)
            asm volatile("" : "+a"(wfrag[gate][kt]));   // pin in AGPRs

    // n-gate hidden bias, f16 (r/z folded into xW bias by the GEMM)
    f16x4 bn4 = *(const f16x4*)(bhn16 + g * 256 + wv * 16 + quad * 4);

    // h double buffer: 2 x 16 batches x 256 f16 (512B rows, no pad).
    // Swizzle: within a row, 16B slot s stored at s ^ (row&7). Applied on
    // write AND read -> bijective & consistent. Banks: row stride 512B == 0
    // mod 32 banks, so the XOR is what spreads the 16-lane phase groups.
    __shared__ __align__(16) f16 h2[8192];   // 16 KiB, buffer 1 at byte 8192
    char* lds = (char*)h2;
    for (int idx = t; idx < 4096; idx += 1024) h2[idx] = (f16)0.f;  // zero buf0

    unsigned rowb  = l16 << 9;
    unsigned qx    = (unsigned)(quad ^ (l8 & 3));
    unsigned kx    = (unsigned)((l8 & 4) << 4);
    unsigned roffc = rowb + (qx << 4);                 // + ((kt<<6)^kx) per kt
    unsigned woff  = rowb + ((((wv << 1) | (quad >> 1)) ^ l8) << 4)
                   + ((quad & 1) << 3) + 8192;         // write -> buffer 1 first
    unsigned curoff = 0;

    // xW / hout: uniform base + per-lane 32-bit offset (SADDR+voffset form)
    const f16* xwb = xw_cat + 768 * g;
    unsigned xoff = (unsigned)((bg * 16 + l16) * 512) * XWS + wv * 16 + quad * 4;
    f16* hob = g ? xb16 : xa16;
    unsigned hoff = (unsigned)((bg * 16 + l16) * 512) * 256 + wv * 16 + quad * 4;

    f32x4 hp = {};                       // h(t-1) for this lane's 4 rows
    __syncthreads();

    for (int ts = 0; ts < 512; ++ts) {
        // xW for THIS step: ~2000cy of MFMA+LDS ahead of the gate use
        uint2 xru = *(const uint2*)(xwb + xoff);
        uint2 xzu = *(const uint2*)(xwb + xoff + 256);
        uint2 xnu = *(const uint2*)(xwb + xoff + 512);
        xoff += XWS;

        f32x4 ar = {}, az = {}, an = {};
        {   // kt = 0 (chain heads carry the VALU->SrcC hazard nop)
            f16x8 bf = *(const f16x8*)(lds + (curoff + roffc + (0u ^ kx)));
            mfma16<1>(ar, wfrag[0][0], bf);
            mfma16<1>(az, wfrag[1][0], bf);
            mfma16<1>(an, wfrag[2][0], bf);
        }
#pragma unroll
        for (int kt = 1; kt < 7; ++kt) {
            f16x8 bf = *(const f16x8*)(lds + (curoff + roffc + (((unsigned)kt << 6) ^ kx)));
            mfma16<0>(ar, wfrag[0][kt], bf);
            mfma16<0>(az, wfrag[1][kt], bf);
            mfma16<0>(an, wfrag[2][kt], bf);
        }
        {   // kt = 7 (tail carries MFMA->accvgpr_read hazard nops)
            f16x8 bf = *(const f16x8*)(lds + (curoff + roffc + ((7u << 6) ^ kx)));
            mfma16<0>(ar, wfrag[0][7], bf);
            mfma16<0>(az, wfrag[1][7], bf);
            mfma16<2>(an, wfrag[2][7], bf);
        }

        f16x4 x4r = __builtin_bit_cast(f16x4, xru);
        f16x4 x4z = __builtin_bit_cast(f16x4, xzu);
        f16x4 x4n = __builtin_bit_cast(f16x4, xnu);
        f16x4 hq;
#pragma unroll
        for (int q = 0; q < 4; ++q) {
            float r = sigmoid_f((float)x4r[q] + ar[q]);          // bhh_r folded
            float z = sigmoid_f((float)x4z[q] + az[q]);          // bhh_z folded
            float n = tanh_f((float)x4n[q] + r * (an[q] + (float)bn4[q]));
            float h = z * (hp[q] - n) + n;                       // (1-z)n + zh
            hp[q] = h;
            hq[q] = (f16)h;
        }
        *(f16x4*)(lds + woff) = hq;                  // h(t) -> other buffer
        *(uint2*)(hob + hoff) = __builtin_bit_cast(uint2, hq);
        hoff += 256;
        __syncthreads();
        curoff ^= 8192; woff ^= 8192;
    }
}

// ---------------------------------------------------------------- scores GEMV
// scores[b,t] = xa[b,t,:] . Wa   (deferred from the recurrence loop)
__global__ __launch_bounds__(256) void scores_kernel(
    const f16* __restrict__ xa16, const float* __restrict__ Wa, float* __restrict__ scores)
{
    int b = blockIdx.x;          // 128 blocks
    int t = threadIdx.x;         // 4 waves
    int wv = t >> 6, l = t & 63;
    float wa0 = Wa[l * 4 + 0];
    float wa1 = Wa[l * 4 + 1];
    float wa2 = Wa[l * 4 + 2];
    float wa3 = Wa[l * 4 + 3];
    const f16* base = xa16 + (size_t)b * 512 * 256;
    for (int row = wv; row < 512; row += 4) {
        const f16* rp = base + (size_t)row * 256 + l * 4;
        uint2 u = *(const uint2*)rp;
        f16x2 p0 = __builtin_bit_cast(f16x2, u.x);
        f16x2 p1 = __builtin_bit_cast(f16x2, u.y);
        float s = (float)p0.x * wa0 + (float)p0.y * wa1
                + (float)p1.x * wa2 + (float)p1.y * wa3;
#pragma unroll
        for (int off = 32; off; off >>= 1) s += __shfl_xor(s, off);
        if (l == 0) scores[b * 512 + row] = s;
    }
}

// ---------------------------------------------------------------- attention
// Running-scan prefix softmax. Grid (128 batches, 2 h-halves) x 128 threads.
__global__ __launch_bounds__(128) void attn_kernel(
    const float* __restrict__ scores, const f16* __restrict__ v16, float* __restrict__ out)
{
    int b = blockIdx.x, tx = threadIdx.x;
    int h = blockIdx.y * 128 + tx;
    __shared__ float wle[512];
    __shared__ float red[2];

    float s0 = scores[b * 512 + tx];
    float s1 = scores[b * 512 + 128 + tx];
    float s2 = scores[b * 512 + 256 + tx];
    float s3 = scores[b * 512 + 384 + tx];
    float m = fmaxf(fmaxf(s0, s1), fmaxf(s2, s3));
#pragma unroll
    for (int off = 32; off; off >>= 1) m = fmaxf(m, __shfl_down(m, off));
    if ((tx & 63) == 0) red[tx >> 6] = m;
    __syncthreads();
    m = fmaxf(red[0], red[1]);
    wle[tx]       = __expf(s0 - m);
    wle[tx + 128] = __expf(s1 - m);
    wle[tx + 256] = __expf(s2 - m);
    wle[tx + 384] = __expf(s3 - m);
    __syncthreads();

    float acc = 0.f, Wc = 0.f;
    const f16* vb = v16 + (size_t)b * 512 * 256 + h;
    float* ob = out + (size_t)b * 512 * 256 + h;
    for (int t8 = 0; t8 < 64; ++t8) {
        float vv[8];
#pragma unroll
        for (int u = 0; u < 8; ++u) vv[u] = (float)vb[(size_t)(t8 * 8 + u) * 256];
#pragma unroll
        for (int u = 0; u < 8; ++u) {
            float wv = wle[t8 * 8 + u];
            Wc += wv;
            acc += wv * vv[u];
            ob[(size_t)(t8 * 8 + u) * 256] = acc * __builtin_amdgcn_rcpf(Wc);
        }
    }
}

// ---------------------------------------------------------------- launch
extern "C" void kernel_launch(void* const* d_in, const int* in_sizes, int n_in,
                              void* d_out, int out_size, void* d_ws, size_t ws_size,
                              hipStream_t stream) {
    const float* x     = (const float*)d_in[0];
    const float* Wp    = (const float*)d_in[1];
    const float* bp    = (const float*)d_in[2];
    const float* Wih_a = (const float*)d_in[3];
    const float* Whh_a = (const float*)d_in[4];
    const float* bih_a = (const float*)d_in[5];
    const float* bhh_a = (const float*)d_in[6];
    const float* Wih_b = (const float*)d_in[7];
    const float* Whh_b = (const float*)d_in[8];
    const float* bih_b = (const float*)d_in[9];
    const float* bhh_b = (const float*)d_in[10];
    const float* Wa    = (const float*)d_in[11];
    // d_in[12] = ba: dropped — softmax is shift-invariant.
    const float* Wb    = (const float*)d_in[13];
    const float* bb    = (const float*)d_in[14];
    float* out = (float*)d_out;

    char* ws = (char*)d_ws;
    size_t off = 0;
    auto take = [&](size_t bytes) -> void* {
        void* p = ws + off;
        off += (bytes + 255) & ~(size_t)255;
        return p;
    };
    f16* xp16     = (f16*)take(16777216ull * 2);      // xp [65536,256] f16      32 MiB
    char* xw_reg  = (char*)take(100663296ull * 2);    // xW cat [65536,1536] f16 192 MiB
    f16* xw_cat16 = (f16*)xw_reg;
    f16* v16      = (f16*)xw_reg;                     // alias (xW dead after rnn)
    float* scores = (float*)take(65536ull * 4);
    f16* wp16     = (f16*)take(32768ull * 2);
    f16* wih_cat  = (f16*)take(393216ull * 2);        // rows 0..767 = a, 768..1535 = b
    f16* whha16   = (f16*)take(196608ull * 2);
    f16* whhb16   = (f16*)take(196608ull * 2);
    f16* wb16     = (f16*)take(65536ull * 2);
    float* bias_cat = (float*)take(1536ull * 4);      // bih + bhh(r,z thirds)
    f16* bhn16    = (f16*)take(512ull * 2);           // (f16)bhh_n, [2 GRUs][256]
    // d_out is [65536,256] f32 = 64 MiB. Lower 32 MiB: xb16 (f16). Upper 32 MiB:
    // xa16 (f16, only needed for the scores GEMV). attn overwrites d_out last.
    f16* xb16 = (f16*)d_out;
    f16* xa16 = (f16*)((char*)d_out + 33554432ull);
    (void)ws_size; (void)n_in; (void)in_sizes; (void)out_size;

    hipLaunchKernelGGL(cvt_weights_kernel, dim3(866), dim3(256), 0, stream,
                       Wp, Wih_a, Whh_a, Wih_b, Whh_b, Wb,
                       bih_a, bhh_a, bih_b, bhh_b,
                       wp16, wih_cat, whha16, wih_cat + 768 * 256, whhb16, wb16,
                       bias_cat, bhn16);
    hipLaunchKernelGGL((gemm_kernel<128, 256, 0, true, (1 << 30)>), dim3(512, 2), dim3(256), 0, stream,
                       (const void*)x, wp16, bp, bp, xp16, (const f16*)nullptr);
    hipLaunchKernelGGL((gemm_kernel<256, 1536, 1, false, (1 << 30)>), dim3(512, 12), dim3(256), 0, stream,
                       (const void*)xp16, wih_cat, bias_cat, bias_cat, xw_cat16, (const f16*)nullptr);
    hipLaunchKernelGGL(rnn_kernel, dim3(16), dim3(1024), 0, stream,
                       xw_cat16, whha16, whhb16, bhn16, xa16, xb16);
    hipLaunchKernelGGL(scores_kernel, dim3(128), dim3(256), 0, stream, xa16, Wa, scores);
    hipLaunchKernelGGL((gemm_kernel<256, 256, 2, false, (1 << 30)>), dim3(512, 2), dim3(256), 0, stream,
                       (const void*)xb16, wb16, bb, bb, v16, xp16);
    hipLaunchKernelGGL(attn_kernel, dim3(128, 2), dim3(128), 0, stream, scores, v16, out);
}

// Round 8
// 2198.768 us; speedup vs baseline: 1.3409x; 1.3409x over previous
//
#include <hip/hip_runtime.h>
#include <hip/hip_bf16.h>

typedef _Float16 f16;
typedef f16 f16x2 __attribute__((ext_vector_type(2)));
typedef f16 f16x4 __attribute__((ext_vector_type(4)));
typedef f16 f16x8 __attribute__((ext_vector_type(8)));
typedef float f32x4 __attribute__((ext_vector_type(4)));

__device__ __forceinline__ float sigmoid_f(float x) {
    return __builtin_amdgcn_rcpf(1.f + __expf(-x));
}
__device__ __forceinline__ float tanh_f(float x) {
    return 1.f - 2.f * __builtin_amdgcn_rcpf(__expf(2.f * x) + 1.f);
}

// ------------------------------------------------- fused weight f32->f16 convert
// bias_cat[1536] = bih + (bhh for r,z thirds); bhn16[512] = (f16)bhh_n per GRU.
// Weight float4 count is 221184 (Wb = 256x256 = 16384 float4).
__global__ __launch_bounds__(256) void cvt_weights_kernel(
    const float* __restrict__ wp, const float* __restrict__ wia, const float* __restrict__ wha,
    const float* __restrict__ wib, const float* __restrict__ whb, const float* __restrict__ wb,
    const float* __restrict__ bia, const float* __restrict__ bha,
    const float* __restrict__ bib, const float* __restrict__ bhb,
    f16* __restrict__ o_wp, f16* __restrict__ o_wia, f16* __restrict__ o_wha,
    f16* __restrict__ o_wib, f16* __restrict__ o_whb, f16* __restrict__ o_wb,
    float* __restrict__ bias_cat, f16* __restrict__ bhn16)
{
    int i = blockIdx.x * 256 + threadIdx.x;
    if (i < 221184) {
        const float* s; f16* d; int off;
        if      (i < 8192)   { s = wp;  d = o_wp;  off = i; }
        else if (i < 57344)  { s = wia; d = o_wia; off = i - 8192; }
        else if (i < 106496) { s = wha; d = o_wha; off = i - 57344; }
        else if (i < 155648) { s = wib; d = o_wib; off = i - 106496; }
        else if (i < 204800) { s = whb; d = o_whb; off = i - 155648; }
        else                 { s = wb;  d = o_wb;  off = i - 204800; }
        float4 f = ((const float4*)s)[off];
        f16x2 p0; p0.x = (f16)f.x; p0.y = (f16)f.y;
        f16x2 p1; p1.x = (f16)f.z; p1.y = (f16)f.w;
        ((f16x2*)d)[off * 2]     = p0;
        ((f16x2*)d)[off * 2 + 1] = p1;
    } else if (i < 221568) {
        int c0 = (i - 221184) * 4;
        float4 v;
        float* pv = (float*)&v;
#pragma unroll
        for (int u = 0; u < 4; ++u) {
            int c = c0 + u;
            int g = c >= 768;
            int local = c - 768 * g;
            const float* bi = g ? bib : bia;
            const float* bh = g ? bhb : bha;
            float val = bi[local];
            if (local < 512) val += bh[local];
            pv[u] = val;
        }
        *(float4*)(bias_cat + c0) = v;
    } else if (i < 221696) {
        int c0 = (i - 221568) * 4;
        f16x4 v;
#pragma unroll
        for (int u = 0; u < 4; ++u) {
            int c = c0 + u;
            int g = c >= 256;
            int local = c - 256 * g;
            const float* bh = g ? bhb : bha;
            v[u] = (f16)bh[512 + local];
        }
        *(f16x4*)(bhn16 + c0) = v;
    }
}

// ---------------------------------------------------------------- MFMA GEMM
#define BM 128
#define BN 128
#define BKC 64
#define LPAD 8

template <int KT, int NOUT, int EPI, bool CVTA, int BSPLIT>
__global__ __launch_bounds__(256) void gemm_kernel(
    const void* __restrict__ Araw, const f16* __restrict__ B,
    const float* __restrict__ bias, const float* __restrict__ bias2,
    f16* __restrict__ out16, const f16* __restrict__ xp16)
{
    __shared__ __align__(16) f16 As[BM][BKC + LPAD];
    __shared__ __align__(16) f16 Bs[BN][BKC + LPAD];
    int tid = threadIdx.x;
    int m0 = blockIdx.x * BM, n0 = blockIdx.y * BN;
    int wave = tid >> 6, lane = tid & 63;
    int wm = (wave & 1) * 64, wn = (wave >> 1) * 64;
    int quad = lane >> 4, l16 = lane & 15;

    f32x4 acc[4][4] = {};

    for (int kc = 0; kc < KT / BKC; ++kc) {
        __syncthreads();
#pragma unroll
        for (int i = 0; i < 4; ++i) {
            int idx = i * 256 + tid;
            int row = idx >> 3, c8 = idx & 7;
            if (CVTA) {
                const float* A32 = (const float*)Araw;
                const float* src = A32 + (size_t)(m0 + row) * KT + kc * BKC + c8 * 8;
                float4 fa = *(const float4*)src;
                float4 fb = *(const float4*)(src + 4);
                f16x8 h8;
                h8[0] = (f16)fa.x; h8[1] = (f16)fa.y; h8[2] = (f16)fa.z; h8[3] = (f16)fa.w;
                h8[4] = (f16)fb.x; h8[5] = (f16)fb.y; h8[6] = (f16)fb.z; h8[7] = (f16)fb.w;
                *(f16x8*)&As[row][c8 * 8] = h8;
            } else {
                const f16* A16 = (const f16*)Araw;
                uint4 va = *(const uint4*)(A16 + (size_t)(m0 + row) * KT + kc * BKC + c8 * 8);
                *(uint4*)&As[row][c8 * 8] = va;
            }
            uint4 vb = *(const uint4*)(B + (size_t)(n0 + row) * KT + kc * BKC + c8 * 8);
            *(uint4*)&Bs[row][c8 * 8] = vb;
        }
        __syncthreads();
#pragma unroll
        for (int kk = 0; kk < 2; ++kk) {
            f16x8 af[4], bf[4];
#pragma unroll
            for (int i = 0; i < 4; ++i) {
                af[i] = *(const f16x8*)&As[wm + i * 16 + l16][kk * 32 + quad * 8];
                bf[i] = *(const f16x8*)&Bs[wn + i * 16 + l16][kk * 32 + quad * 8];
            }
#pragma unroll
            for (int mi = 0; mi < 4; ++mi)
#pragma unroll
                for (int ni = 0; ni < 4; ++ni)
                    acc[mi][ni] = __builtin_amdgcn_mfma_f32_16x16x32_f16(af[mi], bf[ni], acc[mi][ni], 0, 0, 0);
        }
    }

#pragma unroll
    for (int ni = 0; ni < 4; ++ni) {
        int col = n0 + wn + ni * 16 + l16;
        float bv = (col < BSPLIT) ? bias[col] : bias2[col - BSPLIT];
#pragma unroll
        for (int mi = 0; mi < 4; ++mi) {
#pragma unroll
            for (int r = 0; r < 4; ++r) {
                int row = m0 + wm + mi * 16 + quad * 4 + r;
                float val = acc[mi][ni][r] + bv;
                if (EPI == 2) {
                    float tb = tanh_f(val);
                    float xpv = (float)xp16[(size_t)row * NOUT + col];
                    out16[(size_t)row * NOUT + col] = (f16)(tb * xpv);
                } else {
                    out16[(size_t)row * NOUT + col] = (f16)val;
                }
            }
        }
    }
}

// ---------------------------------------------------------------- GRU recurrence
// ROUND-8: MFMA recurrence, 512-thread blocks for a 256-VGPR budget.
// r6 lesson (builtin, 1024 thr): 128-reg cap forced wfrag into AGPRs ->
// 4 v_accvgpr_read per MFMA (286 VALU instr/wave/step measured). r7 lesson
// (asm "a" pins): volatile serialized the LDS->MFMA chains and the dropped
// prefetch exposed ~900cy HBM latency. Fix both structurally: 16 blocks x
// 512 threads (8 waves = 2/SIMD, waves_per_eu(2,2) -> 256 VGPRs). Wave wv
// owns TWO 16-row tiles (rows [wv*32,wv*32+32)) x 3 gates: wfrag[2][3][8]
// = 192 regs + 24 acc + temps ~= 246 <= 256: all arch-resident, plain
// builtin MFMA, no pins, compiler free to interleave. Same per-SIMD MFMA
// count as r6 (96/step), 6 independent acc chains/wave for ILP. xW prefetch
// restored (issue for ts+1 after gates; consumed after next MFMA phase).
// LDS layout identical to r6 (numerically proven).
#define XWS 1536

__global__ __launch_bounds__(512)
__attribute__((amdgpu_waves_per_eu(2, 2)))
void rnn_kernel(
    const f16* __restrict__ xw_cat,
    const f16* __restrict__ whha, const f16* __restrict__ whhb,
    const f16* __restrict__ bhn16,
    f16* __restrict__ xa16, f16* __restrict__ xb16)
{
    int g  = blockIdx.x & 1;
    int bg = blockIdx.x >> 1;            // batch group 0..7 (16 batches each)
    int t = threadIdx.x;
    int wv = t >> 6;                     // wave 0..7: h-rows [wv*32, wv*32+32)
    int lane = t & 63;
    int l16 = lane & 15, quad = lane >> 4;

    const f16* whh = g ? whhb : whha;

    // A-fragments: [tile][gate][kt], lane l:
    //   Whh[gate*256 + wv*32 + tile*16 + l16][kt*32 + quad*8 +: 8]
    f16x8 wfrag[2][3][8];
#pragma unroll
    for (int tile = 0; tile < 2; ++tile)
#pragma unroll
        for (int gate = 0; gate < 3; ++gate) {
            const f16* src = whh + (size_t)(gate * 256 + wv * 32 + tile * 16 + l16) * 256 + quad * 8;
#pragma unroll
            for (int kt = 0; kt < 8; ++kt)
                wfrag[tile][gate][kt] = *(const f16x8*)(src + kt * 32);
        }

    // n-gate hidden bias (f16 table; r/z folded into xW bias by the GEMM)
    f16x4 bn[2];
    bn[0] = *(const f16x4*)(bhn16 + g * 256 + wv * 32 + quad * 4);
    bn[1] = *(const f16x4*)(bhn16 + g * 256 + wv * 32 + 16 + quad * 4);

    // h double buffer: [buf][batch 0..15][264 f16] (proven r6 layout)
    __shared__ __align__(16) f16 h2[2][16][264];
    {
        f16* hz = &h2[0][0][0];
        for (int idx = t; idx < 16 * 264; idx += 512) hz[idx] = (f16)0.f;
    }

    // xW / hout: uniform base + 32-bit per-lane offset
    const f16* xwb = xw_cat + 768 * g;
    unsigned xoff = (unsigned)((bg * 16 + l16) * 512) * XWS + wv * 32 + quad * 4;
    f16* hob = g ? xb16 : xa16;
    unsigned hoff = (unsigned)((bg * 16 + l16) * 512) * 256 + wv * 32 + quad * 4;

    // prefetch xW for ts=0: [tile][gate], 4 f16 each
    uint2 nx[2][3];
#pragma unroll
    for (int tile = 0; tile < 2; ++tile) {
        nx[tile][0] = *(const uint2*)(xwb + xoff + tile * 16);
        nx[tile][1] = *(const uint2*)(xwb + xoff + tile * 16 + 256);
        nx[tile][2] = *(const uint2*)(xwb + xoff + tile * 16 + 512);
    }
    xoff += XWS;

    f32x4 hp[2] = {};                    // h(t-1), lane-resident
    int cur = 0;
    __syncthreads();

    for (int ts = 0; ts < 512; ++ts) {
        f32x4 acc[2][3] = {};            // [tile][gate]
#pragma unroll
        for (int kt = 0; kt < 8; ++kt) {
            f16x8 bf = *(const f16x8*)&h2[cur][l16][kt * 32 + quad * 8];
            acc[0][0] = __builtin_amdgcn_mfma_f32_16x16x32_f16(wfrag[0][0][kt], bf, acc[0][0], 0, 0, 0);
            acc[0][1] = __builtin_amdgcn_mfma_f32_16x16x32_f16(wfrag[0][1][kt], bf, acc[0][1], 0, 0, 0);
            acc[0][2] = __builtin_amdgcn_mfma_f32_16x16x32_f16(wfrag[0][2][kt], bf, acc[0][2], 0, 0, 0);
            acc[1][0] = __builtin_amdgcn_mfma_f32_16x16x32_f16(wfrag[1][0][kt], bf, acc[1][0], 0, 0, 0);
            acc[1][1] = __builtin_amdgcn_mfma_f32_16x16x32_f16(wfrag[1][1][kt], bf, acc[1][1], 0, 0, 0);
            acc[1][2] = __builtin_amdgcn_mfma_f32_16x16x32_f16(wfrag[1][2][kt], bf, acc[1][2], 0, 0, 0);
        }

        // gates: lane-local, 8 h-values (2 tiles x 4 rows), batch = l16
#pragma unroll
        for (int tile = 0; tile < 2; ++tile) {
            f16x4 x4r = __builtin_bit_cast(f16x4, nx[tile][0]);
            f16x4 x4z = __builtin_bit_cast(f16x4, nx[tile][1]);
            f16x4 x4n = __builtin_bit_cast(f16x4, nx[tile][2]);
            f16x4 hq;
#pragma unroll
            for (int q = 0; q < 4; ++q) {
                float r = sigmoid_f((float)x4r[q] + acc[tile][0][q]);   // bhh_r folded
                float z = sigmoid_f((float)x4z[q] + acc[tile][1][q]);   // bhh_z folded
                float n = tanh_f((float)x4n[q] + r * (acc[tile][2][q] + (float)bn[tile][q]));
                float h = z * (hp[tile][q] - n) + n;                    // (1-z)n + zh
                hp[tile][q] = h;
                hq[q] = (f16)h;
            }
            *(f16x4*)&h2[cur ^ 1][l16][wv * 32 + tile * 16 + quad * 4] = hq;
            *(uint2*)(hob + hoff + tile * 16) = __builtin_bit_cast(uint2, hq);
        }
        hoff += 256;

        // prefetch xW for ts+1 (lands during barrier + next MFMA phase;
        // final iteration over-reads into the scores buffer - discarded)
#pragma unroll
        for (int tile = 0; tile < 2; ++tile) {
            nx[tile][0] = *(const uint2*)(xwb + xoff + tile * 16);
            nx[tile][1] = *(const uint2*)(xwb + xoff + tile * 16 + 256);
            nx[tile][2] = *(const uint2*)(xwb + xoff + tile * 16 + 512);
        }
        xoff += XWS;

        __syncthreads();
        cur ^= 1;
    }
}

// ---------------------------------------------------------------- scores GEMV
// scores[b,t] = xa[b,t,:] . Wa   (deferred from the recurrence loop)
__global__ __launch_bounds__(256) void scores_kernel(
    const f16* __restrict__ xa16, const float* __restrict__ Wa, float* __restrict__ scores)
{
    int b = blockIdx.x;          // 128 blocks
    int t = threadIdx.x;         // 4 waves
    int wv = t >> 6, l = t & 63;
    float wa0 = Wa[l * 4 + 0];
    float wa1 = Wa[l * 4 + 1];
    float wa2 = Wa[l * 4 + 2];
    float wa3 = Wa[l * 4 + 3];
    const f16* base = xa16 + (size_t)b * 512 * 256;
    for (int row = wv; row < 512; row += 4) {
        const f16* rp = base + (size_t)row * 256 + l * 4;
        uint2 u = *(const uint2*)rp;
        f16x2 p0 = __builtin_bit_cast(f16x2, u.x);
        f16x2 p1 = __builtin_bit_cast(f16x2, u.y);
        float s = (float)p0.x * wa0 + (float)p0.y * wa1
                + (float)p1.x * wa2 + (float)p1.y * wa3;
#pragma unroll
        for (int off = 32; off; off >>= 1) s += __shfl_xor(s, off);
        if (l == 0) scores[b * 512 + row] = s;
    }
}

// ---------------------------------------------------------------- attention
// Running-scan prefix softmax. Grid (128 batches, 2 h-halves) x 128 threads.
__global__ __launch_bounds__(128) void attn_kernel(
    const float* __restrict__ scores, const f16* __restrict__ v16, float* __restrict__ out)
{
    int b = blockIdx.x, tx = threadIdx.x;
    int h = blockIdx.y * 128 + tx;
    __shared__ float wle[512];
    __shared__ float red[2];

    float s0 = scores[b * 512 + tx];
    float s1 = scores[b * 512 + 128 + tx];
    float s2 = scores[b * 512 + 256 + tx];
    float s3 = scores[b * 512 + 384 + tx];
    float m = fmaxf(fmaxf(s0, s1), fmaxf(s2, s3));
#pragma unroll
    for (int off = 32; off; off >>= 1) m = fmaxf(m, __shfl_down(m, off));
    if ((tx & 63) == 0) red[tx >> 6] = m;
    __syncthreads();
    m = fmaxf(red[0], red[1]);
    wle[tx]       = __expf(s0 - m);
    wle[tx + 128] = __expf(s1 - m);
    wle[tx + 256] = __expf(s2 - m);
    wle[tx + 384] = __expf(s3 - m);
    __syncthreads();

    float acc = 0.f, Wc = 0.f;
    const f16* vb = v16 + (size_t)b * 512 * 256 + h;
    float* ob = out + (size_t)b * 512 * 256 + h;
    for (int t8 = 0; t8 < 64; ++t8) {
        float vv[8];
#pragma unroll
        for (int u = 0; u < 8; ++u) vv[u] = (float)vb[(size_t)(t8 * 8 + u) * 256];
#pragma unroll
        for (int u = 0; u < 8; ++u) {
            float wv = wle[t8 * 8 + u];
            Wc += wv;
            acc += wv * vv[u];
            ob[(size_t)(t8 * 8 + u) * 256] = acc * __builtin_amdgcn_rcpf(Wc);
        }
    }
}

// ---------------------------------------------------------------- launch
extern "C" void kernel_launch(void* const* d_in, const int* in_sizes, int n_in,
                              void* d_out, int out_size, void* d_ws, size_t ws_size,
                              hipStream_t stream) {
    const float* x     = (const float*)d_in[0];
    const float* Wp    = (const float*)d_in[1];
    const float* bp    = (const float*)d_in[2];
    const float* Wih_a = (const float*)d_in[3];
    const float* Whh_a = (const float*)d_in[4];
    const float* bih_a = (const float*)d_in[5];
    const float* bhh_a = (const float*)d_in[6];
    const float* Wih_b = (const float*)d_in[7];
    const float* Whh_b = (const float*)d_in[8];
    const float* bih_b = (const float*)d_in[9];
    const float* bhh_b = (const float*)d_in[10];
    const float* Wa    = (const float*)d_in[11];
    // d_in[12] = ba: dropped — softmax is shift-invariant.
    const float* Wb    = (const float*)d_in[13];
    const float* bb    = (const float*)d_in[14];
    float* out = (float*)d_out;

    char* ws = (char*)d_ws;
    size_t off = 0;
    auto take = [&](size_t bytes) -> void* {
        void* p = ws + off;
        off += (bytes + 255) & ~(size_t)255;
        return p;
    };
    f16* xp16     = (f16*)take(16777216ull * 2);      // xp [65536,256] f16      32 MiB
    char* xw_reg  = (char*)take(100663296ull * 2);    // xW cat [65536,1536] f16 192 MiB
    f16* xw_cat16 = (f16*)xw_reg;
    f16* v16      = (f16*)xw_reg;                     // alias (xW dead after rnn)
    float* scores = (float*)take(65536ull * 4);
    f16* wp16     = (f16*)take(32768ull * 2);
    f16* wih_cat  = (f16*)take(393216ull * 2);        // rows 0..767 = a, 768..1535 = b
    f16* whha16   = (f16*)take(196608ull * 2);
    f16* whhb16   = (f16*)take(196608ull * 2);
    f16* wb16     = (f16*)take(65536ull * 2);
    float* bias_cat = (float*)take(1536ull * 4);      // bih + bhh(r,z thirds)
    f16* bhn16    = (f16*)take(512ull * 2);           // (f16)bhh_n, [2 GRUs][256]
    // d_out is [65536,256] f32 = 64 MiB. Lower 32 MiB: xb16 (f16). Upper 32 MiB:
    // xa16 (f16, only needed for the scores GEMV). attn overwrites d_out last.
    f16* xb16 = (f16*)d_out;
    f16* xa16 = (f16*)((char*)d_out + 33554432ull);
    (void)ws_size; (void)n_in; (void)in_sizes; (void)out_size;

    hipLaunchKernelGGL(cvt_weights_kernel, dim3(866), dim3(256), 0, stream,
                       Wp, Wih_a, Whh_a, Wih_b, Whh_b, Wb,
                       bih_a, bhh_a, bih_b, bhh_b,
                       wp16, wih_cat, whha16, wih_cat + 768 * 256, whhb16, wb16,
                       bias_cat, bhn16);
    hipLaunchKernelGGL((gemm_kernel<128, 256, 0, true, (1 << 30)>), dim3(512, 2), dim3(256), 0, stream,
                       (const void*)x, wp16, bp, bp, xp16, (const f16*)nullptr);
    hipLaunchKernelGGL((gemm_kernel<256, 1536, 1, false, (1 << 30)>), dim3(512, 12), dim3(256), 0, stream,
                       (const void*)xp16, wih_cat, bias_cat, bias_cat, xw_cat16, (const f16*)nullptr);
    hipLaunchKernelGGL(rnn_kernel, dim3(16), dim3(512), 0, stream,
                       xw_cat16, whha16, whhb16, bhn16, xa16, xb16);
    hipLaunchKernelGGL(scores_kernel, dim3(128), dim3(256), 0, stream, xa16, Wa, scores);
    hipLaunchKernelGGL((gemm_kernel<256, 256, 2, false, (1 << 30)>), dim3(512, 2), dim3(256), 0, stream,
                       (const void*)xb16, wb16, bb, bb, v16, xp16);
    hipLaunchKernelGGL(attn_kernel, dim3(128, 2), dim3(128), 0, stream, scores, v16, out);
}

// Round 9
// 926.159 us; speedup vs baseline: 3.1834x; 2.3741x over previous
//
#include <hip/hip_runtime.h>
#include <hip/hip_bf16.h>

typedef _Float16 f16;
typedef f16 f16x2 __attribute__((ext_vector_type(2)));
typedef f16 f16x4 __attribute__((ext_vector_type(4)));
typedef f16 f16x8 __attribute__((ext_vector_type(8)));
typedef float f32x4 __attribute__((ext_vector_type(4)));

__device__ __forceinline__ float dot2acc(f16x2 a, f16x2 b, float c) {
    return __builtin_amdgcn_fdot2(a, b, c, false);
}
__device__ __forceinline__ float sigmoid_f(float x) {
    return __builtin_amdgcn_rcpf(1.f + __expf(-x));
}
__device__ __forceinline__ float tanh_f(float x) {
    return 1.f - 2.f * __builtin_amdgcn_rcpf(__expf(2.f * x) + 1.f);
}
// pair-lane DPP shuffle (pure VALU; keeps the LDS pipe free)
template <int CTRL>
__device__ __forceinline__ float dppx(float x) {
    return __builtin_bit_cast(float,
        __builtin_amdgcn_mov_dpp(__builtin_bit_cast(int, x), CTRL, 0xF, 0xF, true));
}
#define DPP_XOR1 0xB1  // quad_perm [1,0,3,2]

// ------------------------------------------------- fused weight f32->f16 convert
// bias_cat[1536] = bih + (bhh for r,z thirds); bhn16[512] = (f16)bhh_n per GRU.
// Weight float4 count is 221184 (Wb = 256x256 = 16384 float4).
__global__ __launch_bounds__(256) void cvt_weights_kernel(
    const float* __restrict__ wp, const float* __restrict__ wia, const float* __restrict__ wha,
    const float* __restrict__ wib, const float* __restrict__ whb, const float* __restrict__ wb,
    const float* __restrict__ bia, const float* __restrict__ bha,
    const float* __restrict__ bib, const float* __restrict__ bhb,
    f16* __restrict__ o_wp, f16* __restrict__ o_wia, f16* __restrict__ o_wha,
    f16* __restrict__ o_wib, f16* __restrict__ o_whb, f16* __restrict__ o_wb,
    float* __restrict__ bias_cat, f16* __restrict__ bhn16)
{
    int i = blockIdx.x * 256 + threadIdx.x;
    if (i < 221184) {
        const float* s; f16* d; int off;
        if      (i < 8192)   { s = wp;  d = o_wp;  off = i; }
        else if (i < 57344)  { s = wia; d = o_wia; off = i - 8192; }
        else if (i < 106496) { s = wha; d = o_wha; off = i - 57344; }
        else if (i < 155648) { s = wib; d = o_wib; off = i - 106496; }
        else if (i < 204800) { s = whb; d = o_whb; off = i - 155648; }
        else                 { s = wb;  d = o_wb;  off = i - 204800; }
        float4 f = ((const float4*)s)[off];
        f16x2 p0; p0.x = (f16)f.x; p0.y = (f16)f.y;
        f16x2 p1; p1.x = (f16)f.z; p1.y = (f16)f.w;
        ((f16x2*)d)[off * 2]     = p0;
        ((f16x2*)d)[off * 2 + 1] = p1;
    } else if (i < 221568) {
        int c0 = (i - 221184) * 4;
        float4 v;
        float* pv = (float*)&v;
#pragma unroll
        for (int u = 0; u < 4; ++u) {
            int c = c0 + u;
            int g = c >= 768;
            int local = c - 768 * g;
            const float* bi = g ? bib : bia;
            const float* bh = g ? bhb : bha;
            float val = bi[local];
            if (local < 512) val += bh[local];
            pv[u] = val;
        }
        *(float4*)(bias_cat + c0) = v;
    } else if (i < 221696) {
        int c0 = (i - 221568) * 4;
        f16x4 v;
#pragma unroll
        for (int u = 0; u < 4; ++u) {
            int c = c0 + u;
            int g = c >= 256;
            int local = c - 256 * g;
            const float* bh = g ? bhb : bha;
            v[u] = (f16)bh[512 + local];
        }
        *(f16x4*)(bhn16 + c0) = v;
    }
}

// ---------------------------------------------------------------- MFMA GEMM
#define BM 128
#define BN 128
#define BKC 64
#define LPAD 8

template <int KT, int NOUT, int EPI, bool CVTA, int BSPLIT>
__global__ __launch_bounds__(256) void gemm_kernel(
    const void* __restrict__ Araw, const f16* __restrict__ B,
    const float* __restrict__ bias, const float* __restrict__ bias2,
    f16* __restrict__ out16, const f16* __restrict__ xp16)
{
    __shared__ __align__(16) f16 As[BM][BKC + LPAD];
    __shared__ __align__(16) f16 Bs[BN][BKC + LPAD];
    int tid = threadIdx.x;
    int m0 = blockIdx.x * BM, n0 = blockIdx.y * BN;
    int wave = tid >> 6, lane = tid & 63;
    int wm = (wave & 1) * 64, wn = (wave >> 1) * 64;
    int quad = lane >> 4, l16 = lane & 15;

    f32x4 acc[4][4] = {};

    for (int kc = 0; kc < KT / BKC; ++kc) {
        __syncthreads();
#pragma unroll
        for (int i = 0; i < 4; ++i) {
            int idx = i * 256 + tid;
            int row = idx >> 3, c8 = idx & 7;
            if (CVTA) {
                const float* A32 = (const float*)Araw;
                const float* src = A32 + (size_t)(m0 + row) * KT + kc * BKC + c8 * 8;
                float4 fa = *(const float4*)src;
                float4 fb = *(const float4*)(src + 4);
                f16x8 h8;
                h8[0] = (f16)fa.x; h8[1] = (f16)fa.y; h8[2] = (f16)fa.z; h8[3] = (f16)fa.w;
                h8[4] = (f16)fb.x; h8[5] = (f16)fb.y; h8[6] = (f16)fb.z; h8[7] = (f16)fb.w;
                *(f16x8*)&As[row][c8 * 8] = h8;
            } else {
                const f16* A16 = (const f16*)Araw;
                uint4 va = *(const uint4*)(A16 + (size_t)(m0 + row) * KT + kc * BKC + c8 * 8);
                *(uint4*)&As[row][c8 * 8] = va;
            }
            uint4 vb = *(const uint4*)(B + (size_t)(n0 + row) * KT + kc * BKC + c8 * 8);
            *(uint4*)&Bs[row][c8 * 8] = vb;
        }
        __syncthreads();
#pragma unroll
        for (int kk = 0; kk < 2; ++kk) {
            f16x8 af[4], bf[4];
#pragma unroll
            for (int i = 0; i < 4; ++i) {
                af[i] = *(const f16x8*)&As[wm + i * 16 + l16][kk * 32 + quad * 8];
                bf[i] = *(const f16x8*)&Bs[wn + i * 16 + l16][kk * 32 + quad * 8];
            }
#pragma unroll
            for (int mi = 0; mi < 4; ++mi)
#pragma unroll
                for (int ni = 0; ni < 4; ++ni)
                    acc[mi][ni] = __builtin_amdgcn_mfma_f32_16x16x32_f16(af[mi], bf[ni], acc[mi][ni], 0, 0, 0);
        }
    }

#pragma unroll
    for (int ni = 0; ni < 4; ++ni) {
        int col = n0 + wn + ni * 16 + l16;
        float bv = (col < BSPLIT) ? bias[col] : bias2[col - BSPLIT];
#pragma unroll
        for (int mi = 0; mi < 4; ++mi) {
#pragma unroll
            for (int r = 0; r < 4; ++r) {
                int row = m0 + wm + mi * 16 + quad * 4 + r;
                float val = acc[mi][ni][r] + bv;
                if (EPI == 2) {
                    float tb = tanh_f(val);
                    float xpv = (float)xp16[(size_t)row * NOUT + col];
                    out16[(size_t)row * NOUT + col] = (f16)(tb * xpv);
                } else {
                    out16[(size_t)row * NOUT + col] = (f16)val;
                }
            }
        }
    }
}

// ---------------------------------------------------------------- GRU recurrence
// ROUND-9: back to the PROVEN r4 dot2 structure (660us rnn), reshaped so the
// weights finally fit the ARCH register file.
// MFMA arc verdict (r6/r7/r8: 1589/2569/1831 vs 660): dead - 16-block MFMA
// has no latency-hiding and the allocator parks weight frags in AGPRs anyway.
// r4's root defect: 1024-thr block => 4 waves/SIMD => 128-reg cap; demand was
// 96 w + ~35 temps = 131 > 128 => w[] split into AGPRs => ~90 v_accvgpr_read
// per step (measured 313 instr/wave/step vs ~220 needed).
// Fix: 256 blocks (1/CU = one (g,b) pair) x 512 threads (8 waves = 2/SIMD,
// waves_per_eu(2,2) => 256-reg budget). Thread t = (j = t>>1, kp = t&1) owns
// rows {j, j+256, j+512} over k-half kp (128 elems) = 192 f16x2 weight regs;
// demand ~220 <= 256 => "+v" pins satisfiable, zero AGPR traffic.
// Butterfly shrinks to ONE DPP stage (lane pairs). LDS h reads are 2-address
// broadcasts (conflict-free). Barrier is raw s_barrier + lgkmcnt(0) ONLY -
// the global h store and xW prefetch no longer vmcnt(0)-drain every step
// (hipcc emits a full drain for __syncthreads - r4 paid it in stall).
#define XWS 1536

__global__ __launch_bounds__(512)
__attribute__((amdgpu_waves_per_eu(2, 2)))
void rnn_kernel(
    const f16* __restrict__ xw_cat,
    const f16* __restrict__ whha, const f16* __restrict__ whhb,
    const f16* __restrict__ bhn16,
    f16* __restrict__ xa16, f16* __restrict__ xb16)
{
    int g = blockIdx.x >> 7, b = blockIdx.x & 127;
    int t = threadIdx.x;
    int kp = t & 1;           // k-half: h-elems [kp*128, kp*128+128)
    int j  = t >> 1;          // h index 0..255

    const f16* whh = g ? whhb : whha;
    const f16* xwp = xw_cat + (size_t)b * 512 * XWS + 768 * g;  // block-uniform
    f16* hop = (g ? xb16 : xa16) + (size_t)b * 512 * 256;       // block-uniform

    // weights: 3 rows (r,z,n of j) x 128 h-elems of half kp = 192 f16x2 regs
    unsigned w[192];
#pragma unroll
    for (int gate = 0; gate < 3; ++gate) {
        const f16* src = whh + (size_t)(j + 256 * gate) * 256 + kp * 128;
#pragma unroll
        for (int q4 = 0; q4 < 16; ++q4) {
            uint4 u = *(const uint4*)(src + q4 * 8);
            w[gate * 64 + q4 * 4 + 0] = u.x;
            w[gate * 64 + q4 * 4 + 1] = u.y;
            w[gate * 64 + q4 * 4 + 2] = u.z;
            w[gate * 64 + q4 * 4 + 3] = u.w;
        }
    }
#pragma unroll
    for (int i = 0; i < 192; ++i) asm volatile("" : "+v"(w[i]));  // pin in VGPRs

    float bn = (float)bhn16[g * 256 + j];  // only n-gate hidden bias survives fold

    // h double buffer: [buf][half][136 f16] (272B row stride: 16B-aligned,
    // halves land on different banks; reads are 2-address broadcasts anyway)
    __shared__ __align__(16) f16 h2[2][2][136];
    if (t < 256) h2[0][t >> 7][t & 127] = (f16)0.f;
    __syncthreads();

    float hprev = 0.f;
    // prefetch xW row for ts=0 (lane pairs load identical values -> coalesced)
    float xr = (float)xwp[j];
    float xz = (float)xwp[j + 256];
    float xn = (float)xwp[j + 512];
    int cur = 0;
    for (int ts = 0; ts < 512; ++ts) {
        // issue next row's loads early; dot phase hides the latency.
        // (final iteration over-reads into the scores buffer - discarded)
        const f16* xwn = xwp + XWS;
        f16 nxr = xwn[j];
        f16 nxz = xwn[j + 256];
        f16 nxn = xwn[j + 512];

        // partial dots over half kp for rows j, j+256, j+512
        const f16* hb = &h2[cur][kp][0];
        float a0 = 0.f, a1 = 0.f, a2 = 0.f;
#pragma unroll
        for (int i8 = 0; i8 < 16; ++i8) {
            uint4 u = *(const uint4*)(hb + i8 * 8);
            f16x2 p0 = __builtin_bit_cast(f16x2, u.x);
            f16x2 p1 = __builtin_bit_cast(f16x2, u.y);
            f16x2 p2 = __builtin_bit_cast(f16x2, u.z);
            f16x2 p3 = __builtin_bit_cast(f16x2, u.w);
            int kc = i8 * 4;
            a0 = dot2acc(p0, __builtin_bit_cast(f16x2, w[kc + 0]), a0);
            a0 = dot2acc(p1, __builtin_bit_cast(f16x2, w[kc + 1]), a0);
            a0 = dot2acc(p2, __builtin_bit_cast(f16x2, w[kc + 2]), a0);
            a0 = dot2acc(p3, __builtin_bit_cast(f16x2, w[kc + 3]), a0);
            a1 = dot2acc(p0, __builtin_bit_cast(f16x2, w[64 + kc + 0]), a1);
            a1 = dot2acc(p1, __builtin_bit_cast(f16x2, w[64 + kc + 1]), a1);
            a1 = dot2acc(p2, __builtin_bit_cast(f16x2, w[64 + kc + 2]), a1);
            a1 = dot2acc(p3, __builtin_bit_cast(f16x2, w[64 + kc + 3]), a1);
            a2 = dot2acc(p0, __builtin_bit_cast(f16x2, w[128 + kc + 0]), a2);
            a2 = dot2acc(p1, __builtin_bit_cast(f16x2, w[128 + kc + 1]), a2);
            a2 = dot2acc(p2, __builtin_bit_cast(f16x2, w[128 + kc + 2]), a2);
            a2 = dot2acc(p3, __builtin_bit_cast(f16x2, w[128 + kc + 3]), a2);
        }
        // single butterfly stage: both pair lanes end with the full sums
        a0 += dppx<DPP_XOR1>(a0);
        a1 += dppx<DPP_XOR1>(a1);
        a2 += dppx<DPP_XOR1>(a2);

        // gate math, duplicated across the pair (no LDS exchange needed)
        float r = sigmoid_f(xr + a0);          // bhh_r folded into xW bias
        float z = sigmoid_f(xz + a1);          // bhh_z folded into xW bias
        float n = tanh_f(xn + r * (a2 + bn));
        float hnew = z * (hprev - n) + n;      // (1-z)*n + z*h
        hprev = hnew;
        xr = (float)nxr; xz = (float)nxz; xn = (float)nxn;
        xwp = xwn;

        f16 h16 = (f16)hnew;
        if (kp == 0) {
            h2[cur ^ 1][j >> 7][j & 127] = h16;
            hop[j] = h16;
        }
        hop += 256;
        // raw barrier: drain LDS only; global store/loads stay in flight
        asm volatile("s_waitcnt lgkmcnt(0)" ::: "memory");
        __builtin_amdgcn_sched_barrier(0);
        __builtin_amdgcn_s_barrier();
        __builtin_amdgcn_sched_barrier(0);
        cur ^= 1;
    }
}

// ---------------------------------------------------------------- scores GEMV
// scores[b,t] = xa[b,t,:] . Wa   (deferred from the recurrence loop)
__global__ __launch_bounds__(256) void scores_kernel(
    const f16* __restrict__ xa16, const float* __restrict__ Wa, float* __restrict__ scores)
{
    int b = blockIdx.x;          // 128 blocks
    int t = threadIdx.x;         // 4 waves
    int wv = t >> 6, l = t & 63;
    float wa0 = Wa[l * 4 + 0];
    float wa1 = Wa[l * 4 + 1];
    float wa2 = Wa[l * 4 + 2];
    float wa3 = Wa[l * 4 + 3];
    const f16* base = xa16 + (size_t)b * 512 * 256;
    for (int row = wv; row < 512; row += 4) {
        const f16* rp = base + (size_t)row * 256 + l * 4;
        uint2 u = *(const uint2*)rp;
        f16x2 p0 = __builtin_bit_cast(f16x2, u.x);
        f16x2 p1 = __builtin_bit_cast(f16x2, u.y);
        float s = (float)p0.x * wa0 + (float)p0.y * wa1
                + (float)p1.x * wa2 + (float)p1.y * wa3;
#pragma unroll
        for (int off = 32; off; off >>= 1) s += __shfl_xor(s, off);
        if (l == 0) scores[b * 512 + row] = s;
    }
}

// ---------------------------------------------------------------- attention
// Running-scan prefix softmax. Grid (128 batches, 2 h-halves) x 128 threads.
__global__ __launch_bounds__(128) void attn_kernel(
    const float* __restrict__ scores, const f16* __restrict__ v16, float* __restrict__ out)
{
    int b = blockIdx.x, tx = threadIdx.x;
    int h = blockIdx.y * 128 + tx;
    __shared__ float wle[512];
    __shared__ float red[2];

    float s0 = scores[b * 512 + tx];
    float s1 = scores[b * 512 + 128 + tx];
    float s2 = scores[b * 512 + 256 + tx];
    float s3 = scores[b * 512 + 384 + tx];
    float m = fmaxf(fmaxf(s0, s1), fmaxf(s2, s3));
#pragma unroll
    for (int off = 32; off; off >>= 1) m = fmaxf(m, __shfl_down(m, off));
    if ((tx & 63) == 0) red[tx >> 6] = m;
    __syncthreads();
    m = fmaxf(red[0], red[1]);
    wle[tx]       = __expf(s0 - m);
    wle[tx + 128] = __expf(s1 - m);
    wle[tx + 256] = __expf(s2 - m);
    wle[tx + 384] = __expf(s3 - m);
    __syncthreads();

    float acc = 0.f, Wc = 0.f;
    const f16* vb = v16 + (size_t)b * 512 * 256 + h;
    float* ob = out + (size_t)b * 512 * 256 + h;
    for (int t8 = 0; t8 < 64; ++t8) {
        float vv[8];
#pragma unroll
        for (int u = 0; u < 8; ++u) vv[u] = (float)vb[(size_t)(t8 * 8 + u) * 256];
#pragma unroll
        for (int u = 0; u < 8; ++u) {
            float wv = wle[t8 * 8 + u];
            Wc += wv;
            acc += wv * vv[u];
            ob[(size_t)(t8 * 8 + u) * 256] = acc * __builtin_amdgcn_rcpf(Wc);
        }
    }
}

// ---------------------------------------------------------------- launch
extern "C" void kernel_launch(void* const* d_in, const int* in_sizes, int n_in,
                              void* d_out, int out_size, void* d_ws, size_t ws_size,
                              hipStream_t stream) {
    const float* x     = (const float*)d_in[0];
    const float* Wp    = (const float*)d_in[1];
    const float* bp    = (const float*)d_in[2];
    const float* Wih_a = (const float*)d_in[3];
    const float* Whh_a = (const float*)d_in[4];
    const float* bih_a = (const float*)d_in[5];
    const float* bhh_a = (const float*)d_in[6];
    const float* Wih_b = (const float*)d_in[7];
    const float* Whh_b = (const float*)d_in[8];
    const float* bih_b = (const float*)d_in[9];
    const float* bhh_b = (const float*)d_in[10];
    const float* Wa    = (const float*)d_in[11];
    // d_in[12] = ba: dropped — softmax is shift-invariant.
    const float* Wb    = (const float*)d_in[13];
    const float* bb    = (const float*)d_in[14];
    float* out = (float*)d_out;

    char* ws = (char*)d_ws;
    size_t off = 0;
    auto take = [&](size_t bytes) -> void* {
        void* p = ws + off;
        off += (bytes + 255) & ~(size_t)255;
        return p;
    };
    f16* xp16     = (f16*)take(16777216ull * 2);      // xp [65536,256] f16      32 MiB
    char* xw_reg  = (char*)take(100663296ull * 2);    // xW cat [65536,1536] f16 192 MiB
    f16* xw_cat16 = (f16*)xw_reg;
    f16* v16      = (f16*)xw_reg;                     // alias (xW dead after rnn)
    float* scores = (float*)take(65536ull * 4);
    f16* wp16     = (f16*)take(32768ull * 2);
    f16* wih_cat  = (f16*)take(393216ull * 2);        // rows 0..767 = a, 768..1535 = b
    f16* whha16   = (f16*)take(196608ull * 2);
    f16* whhb16   = (f16*)take(196608ull * 2);
    f16* wb16     = (f16*)take(65536ull * 2);
    float* bias_cat = (float*)take(1536ull * 4);      // bih + bhh(r,z thirds)
    f16* bhn16    = (f16*)take(512ull * 2);           // (f16)bhh_n, [2 GRUs][256]
    // d_out is [65536,256] f32 = 64 MiB. Lower 32 MiB: xb16 (f16). Upper 32 MiB:
    // xa16 (f16, only needed for the scores GEMV). attn overwrites d_out last.
    f16* xb16 = (f16*)d_out;
    f16* xa16 = (f16*)((char*)d_out + 33554432ull);
    (void)ws_size; (void)n_in; (void)in_sizes; (void)out_size;

    hipLaunchKernelGGL(cvt_weights_kernel, dim3(866), dim3(256), 0, stream,
                       Wp, Wih_a, Whh_a, Wih_b, Whh_b, Wb,
                       bih_a, bhh_a, bih_b, bhh_b,
                       wp16, wih_cat, whha16, wih_cat + 768 * 256, whhb16, wb16,
                       bias_cat, bhn16);
    hipLaunchKernelGGL((gemm_kernel<128, 256, 0, true, (1 << 30)>), dim3(512, 2), dim3(256), 0, stream,
                       (const void*)x, wp16, bp, bp, xp16, (const f16*)nullptr);
    hipLaunchKernelGGL((gemm_kernel<256, 1536, 1, false, (1 << 30)>), dim3(512, 12), dim3(256), 0, stream,
                       (const void*)xp16, wih_cat, bias_cat, bias_cat, xw_cat16, (const f16*)nullptr);
    hipLaunchKernelGGL(rnn_kernel, dim3(256), dim3(512), 0, stream,
                       xw_cat16, whha16, whhb16, bhn16, xa16, xb16);
    hipLaunchKernelGGL(scores_kernel, dim3(128), dim3(256), 0, stream, xa16, Wa, scores);
    hipLaunchKernelGGL((gemm_kernel<256, 256, 2, false, (1 << 30)>), dim3(512, 2), dim3(256), 0, stream,
                       (const void*)xb16, wb16, bb, bb, v16, xp16);
    hipLaunchKernelGGL(attn_kernel, dim3(128, 2), dim3(128), 0, stream, scores, v16, out);
}